// Round 2
// baseline (695.254 us; speedup 1.0000x reference)
//
#include <hip/hip_runtime.h>

typedef unsigned short u16;
typedef unsigned int u32;
typedef __bf16 bf16x8 __attribute__((ext_vector_type(8)));
typedef float f32x4 __attribute__((ext_vector_type(4)));

__device__ inline float bf2f(u16 u) { u32 x = ((u32)u) << 16; return __uint_as_float(x); }
__device__ inline u16 f2bf(float f) {
  u32 x = __float_as_uint(f);
  u32 r = (x + 0x7FFFu + ((x >> 16) & 1u)) >> 16;  // RNE
  return (u16)r;
}

__device__ inline void load_lds16(const void* g, void* l) {
  __builtin_amdgcn_global_load_lds((const __attribute__((address_space(1))) void*)g,
                                   (__attribute__((address_space(3))) void*)l, 16, 0, 0);
}

// ---------------- cast x (f32 -> bf16), vectorized ----------------
__global__ __launch_bounds__(256) void cast_bf16(const float* __restrict__ s,
                                                 u16* __restrict__ d, int n4) {
  const float4* s4 = (const float4*)s;
  u32* d2 = (u32*)d;
  int i = blockIdx.x * 256 + threadIdx.x;
  int stride = gridDim.x * 256;
  for (; i < n4; i += stride) {
    float4 f = s4[i];
    d2[2 * i]     = (u32)f2bf(f.x) | ((u32)f2bf(f.y) << 16);
    d2[2 * i + 1] = (u32)f2bf(f.z) | ((u32)f2bf(f.w) << 16);
  }
}

// ---------------- transpose + cast: src[R][C] f32 -> dst[C][R] bf16 ----------------
__global__ __launch_bounds__(256) void transpose_cast(const float* __restrict__ src,
                                                      u16* __restrict__ dst, int R, int C) {
  __shared__ float tile[32][33];
  int bx = blockIdx.x, by = blockIdx.y;
  int tx = threadIdx.x & 31, ty = threadIdx.x >> 5;  // 8 rows per pass
  for (int rr = ty; rr < 32; rr += 8)
    tile[rr][tx] = src[(size_t)(by * 32 + rr) * C + bx * 32 + tx];
  __syncthreads();
  for (int rr = ty; rr < 32; rr += 8)
    dst[(size_t)(bx * 32 + rr) * R + by * 32 + tx] = f2bf(tile[tx][rr]);
}

// ---------------- bf16 MFMA GEMM: C = A[M,K] * Bt[N,K]^T ----------------
// EPI 0: scatter into q/k/v [(b*16+h), n, 64] bf16 with q*0.125
// EPI 1: out[M,N] f32 = C + bias[col]
template <int EPI>
__global__ __launch_bounds__(256) void gemm_bt(
    const u16* __restrict__ A, const u16* __restrict__ Bt, int M, int N, int K,
    u16* __restrict__ q0, u16* __restrict__ k0, u16* __restrict__ v0,
    float* __restrict__ out, const float* __restrict__ bias) {
  __shared__ u16 Alds[128 * 64];
  __shared__ u16 Blds[128 * 64];
  const int tid = threadIdx.x;
  const int lane = tid & 63;
  const int wave = tid >> 6;
  const int wr = wave >> 1, wc = wave & 1;
  const int lr = lane & 15, lg = lane >> 4;
  const int n0 = blockIdx.x * 128;
  const int m0 = blockIdx.y * 128;
  f32x4 acc[4][4];
#pragma unroll
  for (int m = 0; m < 4; ++m)
#pragma unroll
    for (int n = 0; n < 4; ++n) acc[m][n] = f32x4{0.f, 0.f, 0.f, 0.f};

  for (int kt = 0; kt < K; kt += 64) {
    // stage A[128][64] and Bt[128][64] tiles; XOR-swizzle (slot ^= row&7) applied by
    // pre-swizzling the GLOBAL source (dest stays linear per global_load_lds rules).
#pragma unroll
    for (int it = 0; it < 4; ++it) {
      int c = it * 256 + tid;
      int row = c >> 3, ps = c & 7;
      int ks = ps ^ (row & 7);
      const u16* ga = A + (size_t)(m0 + row) * K + kt + ks * 8;
      const u16* gb = Bt + (size_t)(n0 + row) * K + kt + ks * 8;
      char* la = (char*)Alds + (size_t)(it * 256 + (tid & ~63)) * 16;
      char* lb = (char*)Blds + (size_t)(it * 256 + (tid & ~63)) * 16;
      load_lds16(ga, la);
      load_lds16(gb, lb);
    }
    __syncthreads();
#pragma unroll
    for (int kk = 0; kk < 2; ++kk) {
      bf16x8 afr[4], bfr[4];
#pragma unroll
      for (int m = 0; m < 4; ++m) {
        int rl = wr * 64 + m * 16 + lr;
        int sl = (kk * 4 + lg) ^ (rl & 7);
        afr[m] = *(const bf16x8*)(Alds + rl * 64 + sl * 8);
      }
#pragma unroll
      for (int n = 0; n < 4; ++n) {
        int rl = wc * 64 + n * 16 + lr;
        int sl = (kk * 4 + lg) ^ (rl & 7);
        bfr[n] = *(const bf16x8*)(Blds + rl * 64 + sl * 8);
      }
#pragma unroll
      for (int m = 0; m < 4; ++m)
#pragma unroll
        for (int n = 0; n < 4; ++n)
          acc[m][n] = __builtin_amdgcn_mfma_f32_16x16x32_bf16(afr[m], bfr[n], acc[m][n], 0, 0, 0);
    }
    __syncthreads();
  }

#pragma unroll
  for (int m = 0; m < 4; ++m) {
#pragma unroll
    for (int n = 0; n < 4; ++n) {
      int col = n0 + wc * 64 + n * 16 + lr;
      if (EPI == 0) {
        int p = col >> 10, cc = col & 1023;
        int h = cc >> 6, d = cc & 63;
        u16* dst = (p == 0) ? q0 : (p == 1) ? k0 : v0;
        float sc = (p == 0) ? 0.125f : 1.0f;
#pragma unroll
        for (int jj = 0; jj < 4; ++jj) {
          int row = m0 + wr * 64 + m * 16 + lg * 4 + jj;
          int b = row >> 13, nn = row & 8191;
          dst[((size_t)((b << 4) + h) * 8192 + nn) * 64 + d] = f2bf(acc[m][n][jj] * sc);
        }
      } else {
        float bv = bias[col];
#pragma unroll
        for (int jj = 0; jj < 4; ++jj) {
          int row = m0 + wr * 64 + m * 16 + lg * 4 + jj;
          out[(size_t)row * N + col] = acc[m][n][jj] + bv;
        }
      }
    }
  }
}

// ---------------- pooling: level l-1 -> l (q,k mean; v sum), bf16 ----------------
__global__ __launch_bounds__(256) void pool_level(
    const u16* __restrict__ qs, const u16* __restrict__ ks, const u16* __restrict__ vs,
    u16* __restrict__ qd, u16* __restrict__ kd, u16* __restrict__ vd, int P) {
  int t = blockIdx.x * 256 + threadIdx.x;
  if (t >= P) return;
  int a = blockIdx.y;
  const u32* s = (const u32*)(a == 0 ? qs : a == 1 ? ks : vs);
  u32* d = (u32*)(a == 0 ? qd : a == 1 ? kd : vd);
  int row = t >> 5, dp = t & 31;
  u32 u0 = s[(size_t)(2 * row) * 32 + dp];
  u32 u1 = s[(size_t)(2 * row + 1) * 32 + dp];
  float x0 = bf2f((u16)u0), x1 = bf2f((u16)(u0 >> 16));
  float y0 = bf2f((u16)u1), y1 = bf2f((u16)(u1 >> 16));
  float sc = (a == 2) ? 1.0f : 0.5f;
  d[t] = (u32)f2bf((x0 + y0) * sc) | ((u32)f2bf((x1 + y1) * sc) << 16);
}

// ---------------- per-level attention + upsample-accumulate ----------------
// grid: (N/16, 64); 256 threads. flip: k/v taken from paired block jb^1.
// Level 0 (outA != null): out = Y/(Asum+eps) -> bf16 [b, n, h*64+d].
__global__ __launch_bounds__(256) void hattn_level(
    const u16* __restrict__ q, const u16* __restrict__ k, const u16* __restrict__ v,
    const float* __restrict__ pY, const float* __restrict__ pA,
    float* __restrict__ Ycur, float* __restrict__ Acur,
    u16* __restrict__ outA, int N, int flip) {
  __shared__ float qs[16][68], ks[16][68], vs[16][68];
  __shared__ float As[16][17];
  const int tid = threadIdx.x;
  const int jb = blockIdx.x;
  const int Bi = blockIdx.y;
  const int jk = flip ? (jb ^ 1) : jb;
  const u32* qg = (const u32*)(q + ((size_t)Bi * N + jb * 16) * 64);
  const u32* kg = (const u32*)(k + ((size_t)Bi * N + jk * 16) * 64);
  const u32* vg = (const u32*)(v + ((size_t)Bi * N + jk * 16) * 64);
#pragma unroll
  for (int u = tid; u < 512; u += 256) {
    int row = u >> 5, dp = (u & 31) * 2;
    u32 a = qg[u]; qs[row][dp] = bf2f((u16)a); qs[row][dp + 1] = bf2f((u16)(a >> 16));
    u32 b = kg[u]; ks[row][dp] = bf2f((u16)b); ks[row][dp + 1] = bf2f((u16)(b >> 16));
    u32 c = vg[u]; vs[row][dp] = bf2f((u16)c); vs[row][dp + 1] = bf2f((u16)(c >> 16));
  }
  __syncthreads();
  const int i = tid >> 4, j = tid & 15;
  float s = 0.f;
  const float4* qv = (const float4*)&qs[i][0];
  const float4* kv = (const float4*)&ks[j][0];
#pragma unroll
  for (int d4 = 0; d4 < 16; ++d4) {
    float4 a = qv[d4], b = kv[d4];
    s += a.x * b.x + a.y * b.y + a.z * b.z + a.w * b.w;
  }
  float mx = s;
#pragma unroll
  for (int off = 8; off; off >>= 1) mx = fmaxf(mx, __shfl_xor(mx, off, 16));
  float aexp = __expf(s - mx);
  float asum = aexp;
#pragma unroll
  for (int off = 8; off; off >>= 1) asum += __shfl_xor(asum, off, 16);
  As[i][j] = aexp;
  __syncthreads();
  float y0 = 0, y1 = 0, y2 = 0, y3 = 0;
  const int d0 = j * 4;
#pragma unroll
  for (int jj = 0; jj < 16; ++jj) {
    float av = As[i][jj];
    const float4 vv = *(const float4*)&vs[jj][d0];
    y0 += av * vv.x; y1 += av * vv.y; y2 += av * vv.z; y3 += av * vv.w;
  }
  const int nf = jb * 16 + i;
  float at = asum;
  if (pY) {
    const float* py = pY + ((size_t)Bi * (N >> 1) + (nf >> 1)) * 64 + d0;
    y0 += py[0]; y1 += py[1]; y2 += py[2]; y3 += py[3];
    at += pA[(size_t)Bi * (N >> 1) + (nf >> 1)];
  }
  if (outA) {
    float inv = 1.0f / (at + 1e-8f);
    int b = Bi >> 4, h = Bi & 15;
    u16* o = outA + ((size_t)(b * 8192 + nf) * 1024 + h * 64 + d0);
    o[0] = f2bf(y0 * inv); o[1] = f2bf(y1 * inv);
    o[2] = f2bf(y2 * inv); o[3] = f2bf(y3 * inv);
  } else {
    float* yo = Ycur + ((size_t)Bi * N + nf) * 64 + d0;
    yo[0] = y0; yo[1] = y1; yo[2] = y2; yo[3] = y3;
    if (j == 0) Acur[(size_t)Bi * N + nf] = at;
  }
}

// ---------------- host ----------------
extern "C" void kernel_launch(void* const* d_in, const int* in_sizes, int n_in,
                              void* d_out, int out_size, void* d_ws, size_t ws_size,
                              hipStream_t stream) {
  const float* x = (const float*)d_in[0];
  const float* w_qkv = (const float*)d_in[1];
  const float* w_out = (const float*)d_in[2];
  const float* b_out = (const float*)d_in[3];
  float* out = (float*)d_out;

  char* ws = (char*)d_ws;
  size_t off = 0;
  auto alloc = [&](size_t bytes) -> char* {
    char* p = ws + off;
    off += (bytes + 255) & ~(size_t)255;
    return p;
  };
  // total ~647 MB
  u16* xb = (u16*)alloc(33554432ull * 2);          // x bf16 / later attn-out bf16
  u16* wqkvT = (u16*)alloc(3072ull * 1024 * 2);
  u16* woutT = (u16*)alloc(1024ull * 1024 * 2);
  u16* q0 = (u16*)alloc(67108864ull);
  u16* k0 = (u16*)alloc(67108864ull);
  u16* v0 = (u16*)alloc(67108864ull);
  u16* qc = (u16*)alloc(66846720ull);              // levels 1..8, 64*8160*64 bf16
  u16* kc = (u16*)alloc(66846720ull);
  u16* vc = (u16*)alloc(66846720ull);
  float* Ybuf[2];
  Ybuf[0] = (float*)alloc(67108864ull);
  Ybuf[1] = (float*)alloc(67108864ull);
  float* Abuf[2];
  Abuf[0] = (float*)alloc(1048576ull);
  Abuf[1] = (float*)alloc(1048576ull);
  (void)ws_size; (void)in_sizes; (void)n_in; (void)out_size;

  cast_bf16<<<2048, 256, 0, stream>>>(x, xb, 33554432 / 4);
  transpose_cast<<<dim3(3072 / 32, 1024 / 32), 256, 0, stream>>>(w_qkv, wqkvT, 1024, 3072);
  transpose_cast<<<dim3(1024 / 32, 1024 / 32), 256, 0, stream>>>(w_out, woutT, 1024, 1024);

  gemm_bt<0><<<dim3(3072 / 128, 32768 / 128), 256, 0, stream>>>(
      xb, wqkvT, 32768, 3072, 1024, q0, k0, v0, nullptr, nullptr);

  const u16 *ql[9], *kl[9], *vl[9];
  ql[0] = q0; kl[0] = k0; vl[0] = v0;
  size_t co = 0;
  for (int l = 1; l <= 8; ++l) {
    ql[l] = qc + co; kl[l] = kc + co; vl[l] = vc + co;
    co += (size_t)64 * (8192 >> l) * 64;
  }
  for (int l = 1; l <= 8; ++l) {
    int Nl = 8192 >> l;
    int P = 64 * Nl * 32;
    pool_level<<<dim3((P + 255) / 256, 3), 256, 0, stream>>>(
        ql[l - 1], kl[l - 1], vl[l - 1], (u16*)ql[l], (u16*)kl[l], (u16*)vl[l], P);
  }
  for (int l = 8; l >= 0; --l) {
    int Nl = 8192 >> l;
    const float* pY = (l == 8) ? nullptr : Ybuf[(l + 1) & 1];
    const float* pA = (l == 8) ? nullptr : Abuf[(l + 1) & 1];
    hattn_level<<<dim3(Nl / 16, 64), 256, 0, stream>>>(
        ql[l], kl[l], vl[l], pY, pA,
        (l == 0) ? nullptr : Ybuf[l & 1], (l == 0) ? nullptr : Abuf[l & 1],
        (l == 0) ? xb : nullptr, Nl, (l != 0) ? 1 : 0);
  }
  gemm_bt<1><<<dim3(1024 / 128, 32768 / 128), 256, 0, stream>>>(
      xb, woutT, 32768, 1024, 1024, nullptr, nullptr, nullptr, out, b_out);
}

// Round 3
// 624.024 us; speedup vs baseline: 1.1141x; 1.1141x over previous
//
#include <hip/hip_runtime.h>

typedef unsigned short u16;
typedef unsigned int u32;
typedef __bf16 bf16x8 __attribute__((ext_vector_type(8)));
typedef float f32x4 __attribute__((ext_vector_type(4)));

__device__ inline float bf2f(u16 u) { u32 x = ((u32)u) << 16; return __uint_as_float(x); }
__device__ inline u16 f2bf(float f) {
  u32 x = __float_as_uint(f);
  u32 r = (x + 0x7FFFu + ((x >> 16) & 1u)) >> 16;  // RNE
  return (u16)r;
}

__device__ inline void load_lds16(const void* g, void* l) {
  __builtin_amdgcn_global_load_lds((const __attribute__((address_space(1))) void*)g,
                                   (__attribute__((address_space(3))) void*)l, 16, 0, 0);
}

// ---------------- cast x (f32 -> bf16), vectorized ----------------
__global__ __launch_bounds__(256) void cast_bf16(const float* __restrict__ s,
                                                 u16* __restrict__ d, int n4) {
  const float4* s4 = (const float4*)s;
  u32* d2 = (u32*)d;
  int i = blockIdx.x * 256 + threadIdx.x;
  int stride = gridDim.x * 256;
  for (; i < n4; i += stride) {
    float4 f = s4[i];
    d2[2 * i]     = (u32)f2bf(f.x) | ((u32)f2bf(f.y) << 16);
    d2[2 * i + 1] = (u32)f2bf(f.z) | ((u32)f2bf(f.w) << 16);
  }
}

// ---------------- transpose + cast: src[R][C] f32 -> dst[C][R] bf16 ----------------
__global__ __launch_bounds__(256) void transpose_cast(const float* __restrict__ src,
                                                      u16* __restrict__ dst, int R, int C) {
  __shared__ float tile[32][33];
  int bx = blockIdx.x, by = blockIdx.y;
  int tx = threadIdx.x & 31, ty = threadIdx.x >> 5;
  for (int rr = ty; rr < 32; rr += 8)
    tile[rr][tx] = src[(size_t)(by * 32 + rr) * C + bx * 32 + tx];
  __syncthreads();
  for (int rr = ty; rr < 32; rr += 8)
    dst[(size_t)(bx * 32 + rr) * R + by * 32 + tx] = f2bf(tile[tx][rr]);
}

// ---------------- 256x256 8-phase bf16 MFMA GEMM: C = A[M,K] * Bt[N,K]^T ----------------
// 512 threads = 8 waves (2M x 4N). BK=64. LDS 128 KiB double-buffered.
// Swizzle: 16B slot ^= (row&7), applied on GLOBAL source (dest linear) + on ds_read.
// Counted vmcnt(4) once per K-tile: at each tile boundary exactly the 2 newest
// half-tiles (4 loads, belonging to tile T+2) may remain in flight.
// EPI 0: scatter into q/k/v [(b*16+h), n, 64] bf16 with q*0.125
// EPI 1: out[M,N] f32 = C + bias[col]
template <int EPI>
__global__ __launch_bounds__(512, 2) void gemm8p(
    const u16* __restrict__ A, const u16* __restrict__ Bt, int M, int N, int K, int NB,
    u16* __restrict__ q0, u16* __restrict__ k0, u16* __restrict__ v0,
    float* __restrict__ out, const float* __restrict__ bias) {
  __shared__ u16 lds[2][2][16384];  // [buf][A/B][256 rows * 64 cols], 128 KiB
  const int tid = threadIdx.x;
  const int lane = tid & 63;
  const int wave = tid >> 6;
  const int wm = wave >> 2, wn = wave & 3;
  const int lr = lane & 15, lg = lane >> 4;

  // XCD-aware swizzle (gridDim.x % 8 == 0 for both GEMMs)
  const int nwg = gridDim.x;
  const int bid = blockIdx.x;
  const int swz = (bid & 7) * (nwg >> 3) + (bid >> 3);
  const int m0 = (swz / NB) * 256;
  const int n0 = (swz % NB) * 256;
  const int NT = K >> 6;

  auto stage_half = [&](int buf, int ht, int kt_) {
    const u16* src = (ht < 2) ? A : Bt;
    const int r0 = (ht < 2) ? m0 : n0;
    u16* ldsop = &lds[buf][ht >> 1][0];
#pragma unroll
    for (int ii = 0; ii < 2; ++ii) {
      int c2 = ((ht & 1) * 2 + ii) * 512 + tid;
      int row = c2 >> 3, ps = c2 & 7;
      int ks = ps ^ (row & 7);
      const u16* g = src + (size_t)(r0 + row) * K + kt_ + ks * 8;
      char* l = (char*)ldsop + (size_t)((((ht & 1) * 2 + ii) * 512 + (tid & ~63)) * 16);
      load_lds16(g, l);
    }
  };
  auto rdA = [&](int c, int mf, int kq) -> bf16x8 {
    int rl = wm * 128 + mf * 16 + lr;
    int sl = (kq * 4 + lg) ^ (rl & 7);
    return *(const bf16x8*)(&lds[c][0][rl * 64 + sl * 8]);
  };
  auto rdB = [&](int c, int nf, int kq) -> bf16x8 {
    int rl = wn * 64 + nf * 16 + lr;
    int sl = (kq * 4 + lg) ^ (rl & 7);
    return *(const bf16x8*)(&lds[c][1][rl * 64 + sl * 8]);
  };

  f32x4 acc[8][4];
#pragma unroll
  for (int mf = 0; mf < 8; ++mf)
#pragma unroll
    for (int nf = 0; nf < 4; ++nf) acc[mf][nf] = f32x4{0.f, 0.f, 0.f, 0.f};

  // ---- prologue: tile0 fully -> buf0; tile1 A halves -> buf1; wait tile0.
  stage_half(0, 0, 0); stage_half(0, 1, 0); stage_half(0, 2, 0); stage_half(0, 3, 0);
  const int kt1 = ((NT > 1) ? 1 : 0) * 64;
  stage_half(1, 0, kt1); stage_half(1, 1, kt1);
  asm volatile("s_waitcnt vmcnt(4)" ::: "memory");
  __builtin_amdgcn_s_barrier();
  __builtin_amdgcn_sched_barrier(0);

  for (int T = 0; T < NT; ++T) {
    const int c = T & 1;
    const int ktn  = ((T + 1 < NT) ? T + 1 : NT - 1) * 64;
    const int ktnn = ((T + 2 < NT) ? T + 2 : NT - 1) * 64;

    bf16x8 af[4][2], bA[2][2], bB[2][2], af2[4][2];
    // ---- phase 0: m-frags 0-3 x n-frags 0-1
#pragma unroll
    for (int mf = 0; mf < 4; ++mf) { af[mf][0] = rdA(c, mf, 0); af[mf][1] = rdA(c, mf, 1); }
#pragma unroll
    for (int nf = 0; nf < 2; ++nf) { bA[nf][0] = rdB(c, nf, 0); bA[nf][1] = rdB(c, nf, 1); }
    stage_half(c ^ 1, 2, ktn);  // tile T+1, B-top
    __builtin_amdgcn_s_barrier();
    asm volatile("s_waitcnt lgkmcnt(0)" ::: "memory");
    __builtin_amdgcn_sched_barrier(0);
    __builtin_amdgcn_s_setprio(1);
#pragma unroll
    for (int mf = 0; mf < 4; ++mf)
#pragma unroll
      for (int nf = 0; nf < 2; ++nf)
#pragma unroll
        for (int kq = 0; kq < 2; ++kq)
          acc[mf][nf] = __builtin_amdgcn_mfma_f32_16x16x32_bf16(af[mf][kq], bA[nf][kq], acc[mf][nf], 0, 0, 0);
    __builtin_amdgcn_s_setprio(0);
    __builtin_amdgcn_s_barrier();

    // ---- phase 1: m-frags 0-3 x n-frags 2-3
#pragma unroll
    for (int nf = 0; nf < 2; ++nf) { bB[nf][0] = rdB(c, 2 + nf, 0); bB[nf][1] = rdB(c, 2 + nf, 1); }
    stage_half(c ^ 1, 3, ktn);  // tile T+1, B-bot
    __builtin_amdgcn_s_barrier();
    asm volatile("s_waitcnt lgkmcnt(0)" ::: "memory");
    __builtin_amdgcn_sched_barrier(0);
    __builtin_amdgcn_s_setprio(1);
#pragma unroll
    for (int mf = 0; mf < 4; ++mf)
#pragma unroll
      for (int nf = 0; nf < 2; ++nf)
#pragma unroll
        for (int kq = 0; kq < 2; ++kq)
          acc[mf][2 + nf] = __builtin_amdgcn_mfma_f32_16x16x32_bf16(af[mf][kq], bB[nf][kq], acc[mf][2 + nf], 0, 0, 0);
    __builtin_amdgcn_s_setprio(0);
    __builtin_amdgcn_s_barrier();

    // ---- phase 2: m-frags 4-7 x n-frags 2-3
#pragma unroll
    for (int mf = 0; mf < 4; ++mf) { af2[mf][0] = rdA(c, 4 + mf, 0); af2[mf][1] = rdA(c, 4 + mf, 1); }
    __builtin_amdgcn_s_barrier();
    asm volatile("s_waitcnt lgkmcnt(0)" ::: "memory");
    __builtin_amdgcn_sched_barrier(0);
    __builtin_amdgcn_s_setprio(1);
#pragma unroll
    for (int mf = 0; mf < 4; ++mf)
#pragma unroll
      for (int nf = 0; nf < 2; ++nf)
#pragma unroll
        for (int kq = 0; kq < 2; ++kq)
          acc[4 + mf][2 + nf] = __builtin_amdgcn_mfma_f32_16x16x32_bf16(af2[mf][kq], bB[nf][kq], acc[4 + mf][2 + nf], 0, 0, 0);
    __builtin_amdgcn_s_setprio(0);
    __builtin_amdgcn_s_barrier();

    // ---- phase 3: m-frags 4-7 x n-frags 0-1 (b re-read)
#pragma unroll
    for (int nf = 0; nf < 2; ++nf) { bA[nf][0] = rdB(c, nf, 0); bA[nf][1] = rdB(c, nf, 1); }
    stage_half(c, 0, ktnn);  // tile T+2, A-top (A region of buf c is dead now)
    stage_half(c, 1, ktnn);  // tile T+2, A-bot
    __builtin_amdgcn_s_barrier();
    asm volatile("s_waitcnt lgkmcnt(0)" ::: "memory");
    __builtin_amdgcn_sched_barrier(0);
    __builtin_amdgcn_s_setprio(1);
#pragma unroll
    for (int mf = 0; mf < 4; ++mf)
#pragma unroll
      for (int nf = 0; nf < 2; ++nf)
#pragma unroll
        for (int kq = 0; kq < 2; ++kq)
          acc[4 + mf][nf] = __builtin_amdgcn_mfma_f32_16x16x32_bf16(af2[mf][kq], bA[nf][kq], acc[4 + mf][nf], 0, 0, 0);
    __builtin_amdgcn_s_setprio(0);
    // tile boundary: wait everything except tile T+2's 2 A half-tiles (4 loads)
    asm volatile("s_waitcnt vmcnt(4)" ::: "memory");
    __builtin_amdgcn_s_barrier();
    __builtin_amdgcn_sched_barrier(0);
  }

  // ---- epilogue
#pragma unroll
  for (int mf = 0; mf < 8; ++mf) {
#pragma unroll
    for (int nf = 0; nf < 4; ++nf) {
      int col = n0 + wn * 64 + nf * 16 + lr;
      if (EPI == 0) {
        int p = col >> 10, cc = col & 1023;
        int h = cc >> 6, d = cc & 63;
        u16* dst = (p == 0) ? q0 : (p == 1) ? k0 : v0;
        float sc = (p == 0) ? 0.125f : 1.0f;
#pragma unroll
        for (int jj = 0; jj < 4; ++jj) {
          int row = m0 + wm * 128 + mf * 16 + lg * 4 + jj;
          int b = row >> 13, nn = row & 8191;
          dst[((size_t)((b << 4) + h) * 8192 + nn) * 64 + d] = f2bf(acc[mf][nf][jj] * sc);
        }
      } else {
        float bv = bias[col];
#pragma unroll
        for (int jj = 0; jj < 4; ++jj) {
          int row = m0 + wm * 128 + mf * 16 + lg * 4 + jj;
          out[(size_t)row * N + col] = acc[mf][nf][jj] + bv;
        }
      }
    }
  }
}

// ---------------- fused pooling: all 8 levels in one pass ----------------
// grid (32, 64, 3): 256-row level-0 chunk x Bi x {q,k,v}. LDS ping-pong tree.
__global__ __launch_bounds__(256) void pool_all(
    const u16* __restrict__ q0, const u16* __restrict__ k0, const u16* __restrict__ v0,
    u16* __restrict__ qc, u16* __restrict__ kc, u16* __restrict__ vc) {
  __shared__ u32 bufA[8192];  // 256 rows x 32 u32 (64 bf16)
  __shared__ u32 bufB[4096];
  const int tid = threadIdx.x;
  const int ci = blockIdx.x, Bi = blockIdx.y, arr = blockIdx.z;
  const u32* src = (const u32*)(arr == 0 ? q0 : arr == 1 ? k0 : v0);
  u32* dstb = (u32*)(arr == 0 ? qc : arr == 1 ? kc : vc);
  const float sc = (arr == 2) ? 1.0f : 0.5f;
  const u32* g = src + ((size_t)Bi * 8192 + (size_t)ci * 256) * 32;
#pragma unroll
  for (int i = 0; i < 32; ++i) bufA[i * 256 + tid] = g[i * 256 + tid];
  __syncthreads();
  u32* prev = bufA;
  u32* cur = bufB;
  for (int l = 1; l <= 8; ++l) {
    const int R = 256 >> l;
    u32* dl = dstb + (size_t)2048 * (8192 - (16384 >> l)) +
              ((size_t)Bi * (8192 >> l) + (size_t)ci * R) * 32;
    for (int t = tid; t < R * 32; t += 256) {
      int orow = t >> 5, dp = t & 31;
      u32 u0 = prev[(2 * orow) * 32 + dp];
      u32 u1 = prev[(2 * orow + 1) * 32 + dp];
      float a0 = bf2f((u16)u0), a1 = bf2f((u16)(u0 >> 16));
      float b0 = bf2f((u16)u1), b1 = bf2f((u16)(u1 >> 16));
      u32 r = (u32)f2bf((a0 + b0) * sc) | ((u32)f2bf((a1 + b1) * sc) << 16);
      cur[orow * 32 + dp] = r;
      dl[orow * 32 + dp] = r;
    }
    __syncthreads();
    u32* tmp = prev; prev = cur; cur = tmp;
  }
}

// ---------------- per-level attention + upsample-accumulate ----------------
__global__ __launch_bounds__(256) void hattn_level(
    const u16* __restrict__ q, const u16* __restrict__ k, const u16* __restrict__ v,
    const float* __restrict__ pY, const float* __restrict__ pA,
    float* __restrict__ Ycur, float* __restrict__ Acur,
    u16* __restrict__ outA, int N, int flip) {
  __shared__ float qs[16][68], ks[16][68], vs[16][68];
  __shared__ float As[16][17];
  const int tid = threadIdx.x;
  const int jb = blockIdx.x;
  const int Bi = blockIdx.y;
  const int jk = flip ? (jb ^ 1) : jb;
  const u32* qg = (const u32*)(q + ((size_t)Bi * N + jb * 16) * 64);
  const u32* kg = (const u32*)(k + ((size_t)Bi * N + jk * 16) * 64);
  const u32* vg = (const u32*)(v + ((size_t)Bi * N + jk * 16) * 64);
#pragma unroll
  for (int u = tid; u < 512; u += 256) {
    int row = u >> 5, dp = (u & 31) * 2;
    u32 a = qg[u]; qs[row][dp] = bf2f((u16)a); qs[row][dp + 1] = bf2f((u16)(a >> 16));
    u32 b = kg[u]; ks[row][dp] = bf2f((u16)b); ks[row][dp + 1] = bf2f((u16)(b >> 16));
    u32 c = vg[u]; vs[row][dp] = bf2f((u16)c); vs[row][dp + 1] = bf2f((u16)(c >> 16));
  }
  __syncthreads();
  const int i = tid >> 4, j = tid & 15;
  float s = 0.f;
  const float4* qv = (const float4*)&qs[i][0];
  const float4* kv = (const float4*)&ks[j][0];
#pragma unroll
  for (int d4 = 0; d4 < 16; ++d4) {
    float4 a = qv[d4], b = kv[d4];
    s += a.x * b.x + a.y * b.y + a.z * b.z + a.w * b.w;
  }
  float mx = s;
#pragma unroll
  for (int off = 8; off; off >>= 1) mx = fmaxf(mx, __shfl_xor(mx, off, 16));
  float aexp = __expf(s - mx);
  float asum = aexp;
#pragma unroll
  for (int off = 8; off; off >>= 1) asum += __shfl_xor(asum, off, 16);
  As[i][j] = aexp;
  __syncthreads();
  float y0 = 0, y1 = 0, y2 = 0, y3 = 0;
  const int d0 = j * 4;
#pragma unroll
  for (int jj = 0; jj < 16; ++jj) {
    float av = As[i][jj];
    const float4 vv = *(const float4*)&vs[jj][d0];
    y0 += av * vv.x; y1 += av * vv.y; y2 += av * vv.z; y3 += av * vv.w;
  }
  const int nf = jb * 16 + i;
  float at = asum;
  if (pY) {
    const float* py = pY + ((size_t)Bi * (N >> 1) + (nf >> 1)) * 64 + d0;
    y0 += py[0]; y1 += py[1]; y2 += py[2]; y3 += py[3];
    at += pA[(size_t)Bi * (N >> 1) + (nf >> 1)];
  }
  if (outA) {
    float inv = 1.0f / (at + 1e-8f);
    int b = Bi >> 4, h = Bi & 15;
    u16* o = outA + ((size_t)(b * 8192 + nf) * 1024 + h * 64 + d0);
    o[0] = f2bf(y0 * inv); o[1] = f2bf(y1 * inv);
    o[2] = f2bf(y2 * inv); o[3] = f2bf(y3 * inv);
  } else {
    float* yo = Ycur + ((size_t)Bi * N + nf) * 64 + d0;
    yo[0] = y0; yo[1] = y1; yo[2] = y2; yo[3] = y3;
    if (j == 0) Acur[(size_t)Bi * N + nf] = at;
  }
}

// ---------------- host ----------------
extern "C" void kernel_launch(void* const* d_in, const int* in_sizes, int n_in,
                              void* d_out, int out_size, void* d_ws, size_t ws_size,
                              hipStream_t stream) {
  const float* x = (const float*)d_in[0];
  const float* w_qkv = (const float*)d_in[1];
  const float* w_out = (const float*)d_in[2];
  const float* b_out = (const float*)d_in[3];
  float* out = (float*)d_out;

  char* ws = (char*)d_ws;
  size_t off = 0;
  auto alloc = [&](size_t bytes) -> char* {
    char* p = ws + off;
    off += (bytes + 255) & ~(size_t)255;
    return p;
  };
  u16* xb = (u16*)alloc(33554432ull * 2);
  u16* wqkvT = (u16*)alloc(3072ull * 1024 * 2);
  u16* woutT = (u16*)alloc(1024ull * 1024 * 2);
  u16* q0 = (u16*)alloc(67108864ull);
  u16* k0 = (u16*)alloc(67108864ull);
  u16* v0 = (u16*)alloc(67108864ull);
  u16* qc = (u16*)alloc(66846720ull);
  u16* kc = (u16*)alloc(66846720ull);
  u16* vc = (u16*)alloc(66846720ull);
  float* Ybuf[2];
  Ybuf[0] = (float*)alloc(67108864ull);
  Ybuf[1] = (float*)alloc(67108864ull);
  float* Abuf[2];
  Abuf[0] = (float*)alloc(1048576ull);
  Abuf[1] = (float*)alloc(1048576ull);
  (void)ws_size; (void)in_sizes; (void)n_in; (void)out_size;

  cast_bf16<<<2048, 256, 0, stream>>>(x, xb, 33554432 / 4);
  transpose_cast<<<dim3(3072 / 32, 1024 / 32), 256, 0, stream>>>(w_qkv, wqkvT, 1024, 3072);
  transpose_cast<<<dim3(1024 / 32, 1024 / 32), 256, 0, stream>>>(w_out, woutT, 1024, 1024);

  // QKV GEMM: M=32768, N=3072, K=1024; grid = 128*12 = 1536 blocks (%8==0)
  gemm8p<0><<<1536, 512, 0, stream>>>(xb, wqkvT, 32768, 3072, 1024, 12,
                                      q0, k0, v0, nullptr, nullptr);

  const u16 *ql[9], *kl[9], *vl[9];
  ql[0] = q0; kl[0] = k0; vl[0] = v0;
  size_t co = 0;
  for (int l = 1; l <= 8; ++l) {
    ql[l] = qc + co; kl[l] = kc + co; vl[l] = vc + co;
    co += (size_t)64 * (8192 >> l) * 64;
  }
  pool_all<<<dim3(32, 64, 3), 256, 0, stream>>>(q0, k0, v0, (u16*)qc, (u16*)kc, (u16*)vc);

  for (int l = 8; l >= 0; --l) {
    int Nl = 8192 >> l;
    const float* pY = (l == 8) ? nullptr : Ybuf[(l + 1) & 1];
    const float* pA = (l == 8) ? nullptr : Abuf[(l + 1) & 1];
    hattn_level<<<dim3(Nl / 16, 64), 256, 0, stream>>>(
        ql[l], kl[l], vl[l], pY, pA,
        (l == 0) ? nullptr : Ybuf[l & 1], (l == 0) ? nullptr : Abuf[l & 1],
        (l == 0) ? xb : nullptr, Nl, (l != 0) ? 1 : 0);
  }
  // Out GEMM: M=32768, N=1024, K=1024; grid = 128*4 = 512 blocks (%8==0)
  gemm8p<1><<<512, 512, 0, stream>>>(xb, woutT, 32768, 1024, 1024, 4,
                                     nullptr, nullptr, nullptr, out, b_out);
}